// Round 3
// baseline (624.089 us; speedup 1.0000x reference)
//
#include <hip/hip_runtime.h>
#include <hip/hip_bf16.h>
#include <math.h>

// y[n,o] = min_i (x[n,i] + w[o,i]) + bias[o]
// x: (32768,128) f32, w: (128,128) f32, bias: (128,) f32, out: (32768,128) f32
//
// Key structural fact: w[o][k] is wave-uniform when lanes own ROWS and the
// column loop is in code -> w streams through the SCALAR pipe (s_load) and
// folds into v_add_f32 as the SGPR operand. Zero LDS, zero VALU cost for w.
// x lives per-lane in 128 VGPRs, loaded once. Inner loop is pure VALU:
// 128 v_add + 64 v_min3 per output column.

constexpr int K = 128;

__global__ __launch_bounds__(256, 3)
void minplus_kernel(const float* __restrict__ x,
                    const float* __restrict__ w,
                    const float* __restrict__ bias,
                    float* __restrict__ out)
{
    const int tid  = threadIdx.x;
    const int lane = tid & 63;
    const int wv   = tid >> 6;                 // 0..3

    const int rowtile = blockIdx.x & 511;      // col-half is the HIGH bit so both
    const int colhalf = blockIdx.x >> 9;       // halves of a row-tile share an XCD L2
    const int row = rowtile * 64 + lane;

    // wave-uniform column base; readfirstlane forces the compiler onto the
    // scalar (s_load) path for all w/bias addressing derived from it.
    const int colbase = __builtin_amdgcn_readfirstlane(colhalf * 64 + wv * 16);

    // ---- load my entire x row into registers (32 x float4, static indexing) ----
    float4 xr[32];
    const float4* xrow = reinterpret_cast<const float4*>(x + (size_t)row * K);
    #pragma unroll
    for (int q = 0; q < 32; ++q) xr[q] = xrow[q];

    float* orow = out + (size_t)row * K;

    #pragma unroll 2
    for (int o = 0; o < 16; ++o) {
        const int col = colbase + o;
        const float* __restrict__ wr = w + col * K;   // uniform -> s_load_dwordx16
        float a0 = INFINITY, a1 = INFINITY;           // 2 chains: break dep latency
        #pragma unroll
        for (int q = 0; q < 32; ++q) {
            const float4 xv = xr[q];
            // fminf(fminf(a,b),c) -> v_min3_f32; adds take w as SGPR src
            a0 = fminf(fminf(a0, xv.x + wr[4 * q + 0]), xv.y + wr[4 * q + 1]);
            a1 = fminf(fminf(a1, xv.z + wr[4 * q + 2]), xv.w + wr[4 * q + 3]);
        }
        orow[col] = fminf(a0, a1) + bias[col];
    }
}

extern "C" void kernel_launch(void* const* d_in, const int* in_sizes, int n_in,
                              void* d_out, int out_size, void* d_ws, size_t ws_size,
                              hipStream_t stream) {
    const float* x    = (const float*)d_in[0];
    const float* w    = (const float*)d_in[1];
    const float* bias = (const float*)d_in[2];
    float* out = (float*)d_out;

    int nrows  = in_sizes[0] / K;              // 32768
    int blocks = (nrows / 64) * 2;             // 1024: 512 row-tiles x 2 col-halves
    minplus_kernel<<<blocks, 256, 0, stream>>>(x, w, bias, out);
}

// Round 4
// 43.218 us; speedup vs baseline: 14.4404x; 14.4404x over previous
//
#include <hip/hip_runtime.h>
#include <hip/hip_bf16.h>
#include <math.h>

// y[n,o] = min_i (x[n,i] + w[o,i]) + bias[o]
// x: (32768,128) f32, w: (128,128) f32, bias: (128,) f32, out: (32768,128) f32
//
// Layout: lane owns one output COLUMN (w[col][*] held in 128 VGPRs, loaded
// once, pinned against rematerialization). x rows stream through LDS and are
// read with same-address BROADCAST ds_read_b128 (no conflicts, 16B/inst).
// Stores are coalesced (64 consecutive cols per wave). Inner loop is pure
// VALU: v_add + v_min3 with 4 independent accumulator chains.

constexpr int K = 128;
constexpr int ROWS_PER_BLK = 64;

__global__ __launch_bounds__(256, 2)
void minplus_kernel(const float* __restrict__ x,
                    const float* __restrict__ w,
                    const float* __restrict__ bias,
                    float* __restrict__ out)
{
    __shared__ float xs[ROWS_PER_BLK * K];   // 32 KiB -> 2 blocks/CU (grid-limited)

    const int tid  = threadIdx.x;
    const int lane = tid & 63;
    const int wv   = tid >> 6;               // 0..3
    const int rowbase = blockIdx.x * ROWS_PER_BLK;

    // ---- stage x tile (64 rows x 128) into LDS, coalesced ----
    {
        const float* xsrc = x + (size_t)rowbase * K;
        float4 stg[8];
        #pragma unroll
        for (int p = 0; p < 8; ++p)
            stg[p] = *(const float4*)(xsrc + (size_t)(p * 256 + tid) * 4);
        #pragma unroll
        for (int p = 0; p < 8; ++p)
            *(float4*)(xs + (p * 256 + tid) * 4) = stg[p];
    }

    // ---- my output column; w row into 128 VGPRs, loaded ONCE ----
    const int col = (wv & 1) * 64 + lane;    // waves 0,2 -> cols 0..63; 1,3 -> 64..127
    const int r0  = (wv >> 1) * 32;          // waves 0,1 -> rows 0..31; 2,3 -> 32..63

    float4 wreg[32];
    const float4* wp = (const float4*)(w + (size_t)col * K);
    #pragma unroll
    for (int q = 0; q < 32; ++q) wreg[q] = wp[q];
    // pin w in registers: values become asm-defined -> cannot be rematerialized
    #pragma unroll
    for (int q = 0; q < 32; ++q)
        asm volatile("" : "+v"(wreg[q].x), "+v"(wreg[q].y),
                          "+v"(wreg[q].z), "+v"(wreg[q].w));

    const float bc = bias[col];

    __syncthreads();

    // ---- stream 32 rows, 2 at a time (4 acc chains of ILP) ----
    float* obase = out + (size_t)(rowbase + r0) * K + col;
    for (int r = 0; r < 32; r += 2) {
        const float* xr0 = xs + (r0 + r) * K;   // wave-uniform addr -> LDS broadcast
        const float* xr1 = xr0 + K;
        float a0 = INFINITY, a1 = INFINITY;
        float b0 = INFINITY, b1 = INFINITY;
        #pragma unroll
        for (int q = 0; q < 32; ++q) {
            float4 xa = *(const float4*)(xr0 + q * 4);
            float4 xb = *(const float4*)(xr1 + q * 4);
            float4 wq = wreg[q];
            // fminf(fminf(a,b),c) -> v_min3_f32
            a0 = fminf(fminf(a0, xa.x + wq.x), xa.y + wq.y);
            a1 = fminf(fminf(a1, xa.z + wq.z), xa.w + wq.w);
            b0 = fminf(fminf(b0, xb.x + wq.x), xb.y + wq.y);
            b1 = fminf(fminf(b1, xb.z + wq.z), xb.w + wq.w);
        }
        obase[(size_t)r * K]       = fminf(a0, a1) + bc;
        obase[(size_t)(r + 1) * K] = fminf(b0, b1) + bc;
    }
}

extern "C" void kernel_launch(void* const* d_in, const int* in_sizes, int n_in,
                              void* d_out, int out_size, void* d_ws, size_t ws_size,
                              hipStream_t stream) {
    const float* x    = (const float*)d_in[0];
    const float* w    = (const float*)d_in[1];
    const float* bias = (const float*)d_in[2];
    float* out = (float*)d_out;

    int nrows  = in_sizes[0] / K;            // 32768
    int blocks = nrows / ROWS_PER_BLK;       // 512
    minplus_kernel<<<blocks, 256, 0, stream>>>(x, w, bias, out);
}